// Round 1
// baseline (183.763 us; speedup 1.0000x reference)
//
#include <hip/hip_runtime.h>
#include <math.h>

// CAP = (300+400+900)/300/1000*300400 = 1602.13333...; thresh = 0.2*CAP
#define THRESH 320.42666666666668f
#define T_LEN 96
#define NBLOCKS 2048                 // 2048 blk x 4 waves = 8192 waves = all-resident max

__global__ __launch_bounds__(256) void day_score_kernel(
    const float* __restrict__ pred, const float* __restrict__ tru,
    float* __restrict__ out, int num_days, float scale)
{
    __shared__ float wsum[4];
    const int g = threadIdx.x >> 2;          // day within 64-day group
    const int k = threadIdx.x & 3;           // quarter-line index 0..3

    // Contiguous chunk of days per block: balanced (98 vs 97 days), unlike
    // slab-striding 3125 slabs over 2048 blocks (2:1 tail imbalance).
    const int chunk  = (num_days + (int)gridDim.x - 1) / (int)gridDim.x;
    const int dayBeg = (int)blockIdx.x * chunk;
    int dayEnd = dayBeg + chunk;
    if (dayEnd > num_days) dayEnd = num_days;

    const float4* tru4  = (const float4*)tru;
    const float4* pred4 = (const float4*)pred;

    float acc = 0.0f;   // sum of day-scores (each day counted on 4 lanes; scale has 0.25)

    for (int d0 = dayBeg; d0 < dayEnd; d0 += 64) {
        const int day = d0 + g;
        if (day < dayEnd) {                  // uniform within each 4-lane group
            // Interleaved mapping: float4 idx = day*24 + j*4 + k.
            // A 4-lane group (k=0..3) covers one full 64B cache line per j ->
            // each wave load = 16 fully-consumed lines (was: 96B lane stride,
            // 64 lines x 16B used -> 4x request amplification).
            const float4* tp = tru4  + (size_t)day * 24 + k;
            const float4* pp = pred4 + (size_t)day * 24 + k;

            float s = 0.0f;
#pragma unroll
            for (int j = 0; j < 6; ++j) {
                const float4 tv = tp[j * 4];
                const float4 pv = pp[j * 4];
                float r;
                r = (tv.x - pv.x) * __builtin_amdgcn_rcpf(fmaxf(tv.x, THRESH)); s += r * r;
                r = (tv.y - pv.y) * __builtin_amdgcn_rcpf(fmaxf(tv.y, THRESH)); s += r * r;
                r = (tv.z - pv.z) * __builtin_amdgcn_rcpf(fmaxf(tv.z, THRESH)); s += r * r;
                r = (tv.w - pv.w) * __builtin_amdgcn_rcpf(fmaxf(tv.w, THRESH)); s += r * r;
            }
            // combine the 4 quarter-day partials (lanes of a day are 4-aligned)
            s += __shfl_xor(s, 1);
            s += __shfl_xor(s, 2);
            // all 4 lanes hold the full day sum; all accumulate (fixed by x0.25)
            acc += (1.0f - sqrtf(s * (1.0f / (float)T_LEN))) * 100.0f;
        }
    }

    // wave butterfly: sums all 64 lanes
    acc += __shfl_xor(acc, 1);
    acc += __shfl_xor(acc, 2);
    acc += __shfl_xor(acc, 4);
    acc += __shfl_xor(acc, 8);
    acc += __shfl_xor(acc, 16);
    acc += __shfl_xor(acc, 32);

    const int lane = threadIdx.x & 63;
    const int wave = threadIdx.x >> 6;
    if (lane == 0) wsum[wave] = acc;
    __syncthreads();
    if (threadIdx.x == 0) {
        const float blk = (wsum[0] + wsum[1]) + (wsum[2] + wsum[3]);
        atomicAdd(out, blk * scale);         // NBLOCKS atomics total
    }
}

extern "C" void kernel_launch(void* const* d_in, const int* in_sizes, int n_in,
                              void* d_out, int out_size, void* d_ws, size_t ws_size,
                              hipStream_t stream) {
    (void)n_in; (void)d_ws; (void)ws_size;
    const float* pred = (const float*)d_in[0];   // setup_inputs: {"pred": ..., "true": ...}
    const float* tru  = (const float*)d_in[1];
    float* out = (float*)d_out;

    const int n        = in_sizes[1];
    const int num_days = n / T_LEN;
    const float scale  = 0.25f / (float)num_days;   // 0.25: day counted on 4 lanes

    hipMemsetAsync(out, 0, (size_t)out_size * sizeof(float), stream);
    day_score_kernel<<<NBLOCKS, 256, 0, stream>>>(pred, tru, out, num_days, scale);
}

// Round 2
// 171.259 us; speedup vs baseline: 1.0730x; 1.0730x over previous
//
#include <hip/hip_runtime.h>
#include <math.h>

// CAP = (300+400+900)/300/1000*300400 = 1602.13333...; thresh = 0.2*CAP
#define THRESH 320.42666666666668f
#define T_LEN 96
// 1563 blocks x 128 days = 200064 >= 200000: every block runs 2 full 64-day
// iterations (last block's 2nd iter fully masked). 6252 waves resident (76%).
#define NBLOCKS 1563

// accumulate 4 elements' squared relative error into s
#define ACC4(tv, pv)                                                             \
    do {                                                                         \
        float r;                                                                 \
        r = (tv.x - pv.x) * __builtin_amdgcn_rcpf(fmaxf(tv.x, THRESH)); s += r * r; \
        r = (tv.y - pv.y) * __builtin_amdgcn_rcpf(fmaxf(tv.y, THRESH)); s += r * r; \
        r = (tv.z - pv.z) * __builtin_amdgcn_rcpf(fmaxf(tv.z, THRESH)); s += r * r; \
        r = (tv.w - pv.w) * __builtin_amdgcn_rcpf(fmaxf(tv.w, THRESH)); s += r * r; \
    } while (0)

__global__ __launch_bounds__(256) void day_score_kernel(
    const float* __restrict__ pred, const float* __restrict__ tru,
    float* __restrict__ out, int num_days, float scale)
{
    __shared__ float wsum[4];
    const int g = threadIdx.x >> 2;          // day within 64-day group
    const int k = threadIdx.x & 3;           // quarter-line index 0..3

    const float4* tru4  = (const float4*)tru;
    const float4* pred4 = (const float4*)pred;

    float acc = 0.0f;   // day-score sum (each day on 4 lanes; scale carries 0.25)

    const int dayBeg = (int)blockIdx.x * 128;
#pragma unroll
    for (int it = 0; it < 2; ++it) {
        const int day = dayBeg + it * 64 + g;
        if (day < num_days) {                // uniform within each 4-lane group
            // float4 idx = day*24 + j*4 + k: 4-lane group covers one full 64B
            // line per j (16 fully-used lines per wave-load instruction).
            const float4* tp = tru4  + (size_t)day * 24 + k;
            const float4* pp = pred4 + (size_t)day * 24 + k;

            // Batched loads: 12 independent global_load_dwordx4 issued before
            // ANY consumption -> ~12 KB outstanding per wave (round 1's VGPR=16
            // codegen had ~2 loads in flight; that was the latency wall).
            const float4 t0 = tp[0],  t1 = tp[4],  t2 = tp[8];
            const float4 t3 = tp[12], t4 = tp[16], t5 = tp[20];
            const float4 p0 = pp[0],  p1 = pp[4],  p2 = pp[8];
            const float4 p3 = pp[12], p4 = pp[16], p5 = pp[20];

            float s = 0.0f;
            ACC4(t0, p0); ACC4(t1, p1); ACC4(t2, p2);
            ACC4(t3, p3); ACC4(t4, p4); ACC4(t5, p5);

            // combine the 4 quarter-day partials (lanes of a day are 4-aligned)
            s += __shfl_xor(s, 1);
            s += __shfl_xor(s, 2);
            // all 4 lanes hold the full day sum; all accumulate (fixed by x0.25)
            acc += (1.0f - sqrtf(s * (1.0f / (float)T_LEN))) * 100.0f;
        }
    }

    // wave butterfly: sums all 64 lanes
    acc += __shfl_xor(acc, 1);
    acc += __shfl_xor(acc, 2);
    acc += __shfl_xor(acc, 4);
    acc += __shfl_xor(acc, 8);
    acc += __shfl_xor(acc, 16);
    acc += __shfl_xor(acc, 32);

    const int lane = threadIdx.x & 63;
    const int wave = threadIdx.x >> 6;
    if (lane == 0) wsum[wave] = acc;
    __syncthreads();
    if (threadIdx.x == 0) {
        const float blk = (wsum[0] + wsum[1]) + (wsum[2] + wsum[3]);
        atomicAdd(out, blk * scale);         // NBLOCKS atomics total
    }
}

extern "C" void kernel_launch(void* const* d_in, const int* in_sizes, int n_in,
                              void* d_out, int out_size, void* d_ws, size_t ws_size,
                              hipStream_t stream) {
    (void)n_in; (void)d_ws; (void)ws_size;
    const float* pred = (const float*)d_in[0];   // setup_inputs: {"pred": ..., "true": ...}
    const float* tru  = (const float*)d_in[1];
    float* out = (float*)d_out;

    const int n        = in_sizes[1];
    const int num_days = n / T_LEN;
    const float scale  = 0.25f / (float)num_days;   // 0.25: day counted on 4 lanes

    hipMemsetAsync(out, 0, (size_t)out_size * sizeof(float), stream);
    day_score_kernel<<<NBLOCKS, 256, 0, stream>>>(pred, tru, out, num_days, scale);
}

// Round 3
// 170.879 us; speedup vs baseline: 1.0754x; 1.0022x over previous
//
#include <hip/hip_runtime.h>
#include <math.h>

// CAP = (300+400+900)/300/1000*300400 = 1602.13333...; thresh = 0.2*CAP
#define THRESH 320.42666666666668f
#define NBLOCKS 512          // 2 blocks/CU (LDS-limited), grid-strides over chunks
#define CH_DAYS 32           // days per chunk: 32*96*4B = 12KB per array
#define CH_FLOATS (CH_DAYS * 96)   // 3072
#define DEPTH 3              // 3-slot circular LDS pipeline, 2 chunks prefetch-ahead

typedef const __attribute__((address_space(1))) void* gas_t;  // global
typedef __attribute__((address_space(3))) void*       las_t;  // LDS

// accumulate 4 elements' squared relative error into s
#define ACC4(tv, pv)                                                                \
    do {                                                                            \
        float r;                                                                    \
        r = (tv.x - pv.x) * __builtin_amdgcn_rcpf(fmaxf(tv.x, THRESH)); s += r * r; \
        r = (tv.y - pv.y) * __builtin_amdgcn_rcpf(fmaxf(tv.y, THRESH)); s += r * r; \
        r = (tv.z - pv.z) * __builtin_amdgcn_rcpf(fmaxf(tv.z, THRESH)); s += r * r; \
        r = (tv.w - pv.w) * __builtin_amdgcn_rcpf(fmaxf(tv.w, THRESH)); s += r * r; \
    } while (0)

// Wave w DMA-stages ITS OWN 8-day quarter of a chunk (bytes [w*3072, w*3072+3072)
// per array) -> no cross-wave LDS dependency -> no barriers, per-wave vmcnt only.
// 6 global_load_lds_dwordx4 per wave per chunk (3 per array).
__device__ __forceinline__ void stage_chunk(
    const float* __restrict__ tru, const float* __restrict__ pred,
    float* lds_t, float* lds_p, long day0, int w, int lane)
{
    const size_t base = (size_t)day0 * 96 + (size_t)w * 768;
#pragma unroll
    for (int i = 0; i < 3; ++i) {
        const float* gt = tru  + base + i * 256 + lane * 4;
        const float* gp = pred + base + i * 256 + lane * 4;
        // LDS dest is wave-uniform; lane writes dest + lane*16 (matches source).
        __builtin_amdgcn_global_load_lds((gas_t)(const void*)gt,
                                         (las_t)(void*)(lds_t + w * 768 + i * 256), 16, 0, 0);
        __builtin_amdgcn_global_load_lds((gas_t)(const void*)gp,
                                         (las_t)(void*)(lds_p + w * 768 + i * 256), 16, 0, 0);
    }
}

// Wave w scores its 8 staged days: 8 lanes/day, 12 floats/lane (3 ds_read_b128
// pairs). Bank check: dword addr = dl*96 + k*12 -> the 8 k-slots start at banks
// {0,12,24,4,16,28,8,20}, each b128 spans 4 banks -> exact 32-bank tiling,
// minimum 8-way aliasing for 256 bank-accesses (free).
__device__ __forceinline__ float chunk_score(
    const float* lds_t, const float* lds_p, int w, int lane)
{
    const int dl = w * 8 + (lane >> 3);  // day within chunk
    const int k  = lane & 7;             // 12-float slice within day
    const float4* t4 = (const float4*)(lds_t + dl * 96 + k * 12);
    const float4* p4 = (const float4*)(lds_p + dl * 96 + k * 12);
    float s = 0.0f;
#pragma unroll
    for (int j = 0; j < 3; ++j) {
        const float4 tv = t4[j];
        const float4 pv = p4[j];
        ACC4(tv, pv);
    }
    // fold the 8 k-slices (lane bits 0..2); all 8 lanes of a day get the total
    s += __shfl_xor(s, 1);
    s += __shfl_xor(s, 2);
    s += __shfl_xor(s, 4);
    return (1.0f - sqrtf(s * (1.0f / 96.0f))) * 100.0f;
}

__global__ __launch_bounds__(256) void day_score_kernel(
    const float* __restrict__ pred, const float* __restrict__ tru,
    float* __restrict__ ws, int nchunks)
{
    __shared__ float lds[DEPTH][2][CH_FLOATS];   // 72 KB: 2 blocks/CU
    __shared__ float wsum[4];
    const int tid  = threadIdx.x;
    const int w    = tid >> 6;
    const int lane = tid & 63;
    const int b    = (int)blockIdx.x;

    // grid-stride over chunks: cid = b + j*NBLOCKS (12 or 13 chunks per block)
    const int nmine = (nchunks > b) ? (nchunks - b + NBLOCKS - 1) / NBLOCKS : 0;

    // prologue: fill the pipeline (DEPTH chunks in flight)
    for (int j = 0; j < DEPTH && j < nmine; ++j) {
        const long day0 = (long)(b + j * NBLOCKS) * CH_DAYS;
        stage_chunk(tru, pred, lds[j][0], lds[j][1], day0, w, lane);
    }

    float acc = 0.0f;
    for (int j = 0; j < nmine; ++j) {
        const int ahead = nmine - 1 - j;   // chunks issued beyond j (block-uniform)
        // counted wait: chunk j's 6 DMAs done, newer chunks stay in flight (T4)
        if (ahead >= 2)      { asm volatile("s_waitcnt vmcnt(12)" ::: "memory"); }
        else if (ahead == 1) { asm volatile("s_waitcnt vmcnt(6)"  ::: "memory"); }
        else                 { asm volatile("s_waitcnt vmcnt(0)"  ::: "memory"); }
        __builtin_amdgcn_sched_barrier(0);

        const int slot = j % DEPTH;
        acc += chunk_score(lds[slot][0], lds[slot][1], w, lane);

        asm volatile("" ::: "memory");     // keep ds_reads above the slot refill
        if (j + DEPTH < nmine) {
            const long day0 = (long)(b + (j + DEPTH) * NBLOCKS) * CH_DAYS;
            stage_chunk(tru, pred, lds[slot][0], lds[slot][1], day0, w, lane);
        }
    }

    // fold the 8 day-groups (lane bits 3..5); bits 0..2 already folded per chunk,
    // so each day is counted exactly ONCE in the wave total.
    acc += __shfl_xor(acc, 8);
    acc += __shfl_xor(acc, 16);
    acc += __shfl_xor(acc, 32);
    if (lane == 0) wsum[w] = acc;
    __syncthreads();
    if (tid == 0) ws[b] = (wsum[0] + wsum[1]) + (wsum[2] + wsum[3]);
}

// Final reduce: 512 per-block partials + (dormant here) sub-chunk tail days.
__global__ __launch_bounds__(256) void reduce_kernel(
    const float* __restrict__ ws, const float* __restrict__ pred,
    const float* __restrict__ tru, float* __restrict__ out,
    int num_days, int tail_start, int out_elems)
{
    __shared__ float wsum[4];
    const int tid = threadIdx.x;
    float v = ws[tid] + ws[tid + 256];

    for (int day = tail_start + tid; day < num_days; day += 256) {
        const float4* t4 = (const float4*)(tru  + (size_t)day * 96);
        const float4* p4 = (const float4*)(pred + (size_t)day * 96);
        float s = 0.0f;
#pragma unroll
        for (int j = 0; j < 24; ++j) {
            const float4 tv = t4[j];
            const float4 pv = p4[j];
            ACC4(tv, pv);
        }
        v += (1.0f - sqrtf(s * (1.0f / 96.0f))) * 100.0f;
    }

    v += __shfl_xor(v, 1);
    v += __shfl_xor(v, 2);
    v += __shfl_xor(v, 4);
    v += __shfl_xor(v, 8);
    v += __shfl_xor(v, 16);
    v += __shfl_xor(v, 32);
    if ((tid & 63) == 0) wsum[tid >> 6] = v;
    __syncthreads();
    if (tid == 0)
        out[0] = ((wsum[0] + wsum[1]) + (wsum[2] + wsum[3])) / (float)num_days;
    for (int i = 1 + tid; i < out_elems; i += 256) out[i] = 0.0f;  // keep rest clean
}

extern "C" void kernel_launch(void* const* d_in, const int* in_sizes, int n_in,
                              void* d_out, int out_size, void* d_ws, size_t ws_size,
                              hipStream_t stream) {
    (void)n_in; (void)ws_size;
    const float* pred = (const float*)d_in[0];   // setup_inputs: {"pred": ..., "true": ...}
    const float* tru  = (const float*)d_in[1];
    float* out = (float*)d_out;
    float* ws  = (float*)d_ws;                   // 512 floats of partials

    const int n        = in_sizes[1];
    const int num_days = n / 96;
    const int nchunks  = num_days / CH_DAYS;     // 6250 exactly at num_days=200000

    day_score_kernel<<<NBLOCKS, 256, 0, stream>>>(pred, tru, ws, nchunks);
    reduce_kernel<<<1, 256, 0, stream>>>(ws, pred, tru, out,
                                         num_days, nchunks * CH_DAYS, out_size);
}